// Round 1
// baseline (225.958 us; speedup 1.0000x reference)
//
#include <hip/hip_runtime.h>
#include <math.h>

// RegistrationRender: 6 views x (src,tgt) x 256x256 max-of-gaussians render.
//
// Math: v = pv_k * exp(-5000*d2)  ->  log2 v = log2(pv_k) - C*d2, C = 5000*log2(e)
//  max_k v = exp2(-C * min_k (dx^2 + dy^2 - log2(pv_k)/C))
// Direct (subtract-then-square) d2 avoids cancellation; exp2 underflow for far
// points matches the reference's f32 exp underflow (both -> exactly 0).

#define NPTS 8192
#define HALF 4096
#define WIMG 256
#define CLOG2 7213.475204444817f      // 5000 * log2(e)
#define INV_CLOG2 1.3862943611198906e-4f  // ln(2)/5000

// Rotation matrices: exact f32 casts of numpy float64 cos/sin values.
static __device__ __constant__ float RMAT[6][9] = {
  { 1.f, 0.f, 0.f,   0.f, 1.f, 0.f,   0.f, 0.f, 1.f },                                  // I
  { 6.123233995736766e-17f, 0.f, 1.f,  0.f, 1.f, 0.f,  -1.f, 0.f, 6.123233995736766e-17f }, // Ry(pi/2)
  { -1.f, 0.f, 1.2246467991473532e-16f, 0.f, 1.f, 0.f, -1.2246467991473532e-16f, 0.f, -1.f }, // Ry(pi)
  { -1.8369701987210297e-16f, 0.f, -1.f, 0.f, 1.f, 0.f,  1.f, 0.f, -1.8369701987210297e-16f }, // Ry(3pi/2)
  { 1.f, 0.f, 0.f,  0.f, 6.123233995736766e-17f, -1.f,  0.f, 1.f, 6.123233995736766e-17f }, // Rx(pi/2)
  { 1.f, 0.f, 0.f,  0.f, -1.8369701987210297e-16f, 1.f, 0.f, -1.f, -1.8369701987210297e-16f }, // Rx(3pi/2)
};

// ---------------- kernel 1: rotate, depth min/max, per-point {x, y, -log2(pv)/C}
__global__ __launch_bounds__(256) void prep_kernel(const float* __restrict__ src,
                                                   const float* __restrict__ tgt,
                                                   float4* __restrict__ pts) {
  const int v = blockIdx.x;
  const int tid = threadIdx.x;
  const float* R = RMAT[v];
  const float r20 = R[6], r21 = R[7], r22 = R[8];

  float zmin = 3.0e38f, zmax = -3.0e38f;
  for (int i = tid; i < NPTS; i += 256) {
    const float* p = (i < HALF) ? (src + 3 * i) : (tgt + 3 * (i - HALF));
    const float a = p[0], b = p[1], c = p[2];
    const float z = r20 * a + r21 * b + r22 * c;
    zmin = fminf(zmin, z);
    zmax = fmaxf(zmax, z);
  }
  // wave reduce (64 lanes)
  for (int off = 32; off > 0; off >>= 1) {
    zmin = fminf(zmin, __shfl_down(zmin, off));
    zmax = fmaxf(zmax, __shfl_down(zmax, off));
  }
  __shared__ float smin[4], smax[4];
  const int lane = tid & 63, w = tid >> 6;
  if (lane == 0) { smin[w] = zmin; smax[w] = zmax; }
  __syncthreads();
  const float dmin = fminf(fminf(smin[0], smin[1]), fminf(smin[2], smin[3]));
  const float dmax = fmaxf(fmaxf(smax[0], smax[1]), fmaxf(smax[2], smax[3]));
  const float range = dmax - dmin;

  const float r00 = R[0], r01 = R[1], r02 = R[2];
  const float r10 = R[3], r11 = R[4], r12 = R[5];
  for (int i = tid; i < NPTS; i += 256) {
    const float* p = (i < HALF) ? (src + 3 * i) : (tgt + 3 * (i - HALF));
    const float a = p[0], b = p[1], c = p[2];
    const float x = r00 * a + r01 * b + r02 * c;
    const float y = r10 * a + r11 * b + r12 * c;
    const float z = r20 * a + r21 * b + r22 * c;
    const float pv = 1.0f - (z - dmin) / range;       // same op order as reference
    // -log2(pv)/C : penalty added to d2; pv==0 -> huge penalty -> exp2 -> 0
    const float pen = (pv > 0.f) ? (-log2f(pv) * INV_CLOG2) : 1.0e26f;
    pts[v * NPTS + i] = make_float4(x, y, pen, 0.f);
  }
}

// ---------------- kernel 2: per (view,row,half) min over points, exp2 epilogue
__device__ __forceinline__ void stage_chunk(const float4* __restrict__ base, int c,
                                            float4* __restrict__ dst, int lane, float py) {
  const int p0 = c * 256 + 2 * lane;
  const float4 a0 = base[p0];
  const float4 a1 = base[p0 + 1];
  const float4 b0 = base[p0 + 128];
  const float4 b1 = base[p0 + 129];
  float dy;
  dy = a0.y - py; const float E0 = fmaf(dy, dy, a0.z);
  dy = a1.y - py; const float E1 = fmaf(dy, dy, a1.z);
  dy = b0.y - py; const float E2 = fmaf(dy, dy, b0.z);
  dy = b1.y - py; const float E3 = fmaf(dy, dy, b1.z);
  dst[lane]      = make_float4(E0, a0.x, E1, a1.x);   // {E, x} for 2 points
  dst[64 + lane] = make_float4(E2, b0.x, E3, b1.x);
}

__global__ __launch_bounds__(256) void render_kernel(const float4* __restrict__ pts,
                                                     float* __restrict__ out) {
  __shared__ float4 sbuf[4][2][128];   // [wave][dbuf][2 points per float4]
  const int b = blockIdx.x;            // 768 = 6 views * 128 row-pairs
  const int v = b >> 7, rp = b & 127;
  const int tid = threadIdx.x;
  const int w = tid >> 6, lane = tid & 63;
  const int row = 2 * rp + (w & 1);
  const int h = w >> 1;                // 0 = src half, 1 = tgt half
  const float py  = (row - 127.5f) * 0.0078125f;
  const float px0 = (lane - 127.5f) * 0.0078125f;
  const float px1 = px0 + 0.5f;
  const float px2 = px0 + 1.0f;
  const float px3 = px0 + 1.5f;
  const float4* base = pts + v * NPTS + h * HALF;

  float m0 = 3.0e38f, m1 = 3.0e38f, m2 = 3.0e38f, m3 = 3.0e38f;

  stage_chunk(base, 0, sbuf[w][0], lane, py);
  for (int c = 0; c < 16; ++c) {
    __syncthreads();                               // staging of buf (c&1) visible
    if (c < 15) stage_chunk(base, c + 1, sbuf[w][(c + 1) & 1], lane, py);
    const float4* q = sbuf[w][c & 1];
#pragma unroll 4
    for (int p = 0; p < 128; ++p) {
      const float4 d = q[p];                       // broadcast read: 2 points
      float dx;
      dx = d.y - px0; const float e0 = fmaf(dx, dx, d.x);
      dx = d.y - px1; const float e1 = fmaf(dx, dx, d.x);
      dx = d.y - px2; const float e2 = fmaf(dx, dx, d.x);
      dx = d.y - px3; const float e3 = fmaf(dx, dx, d.x);
      dx = d.w - px0; const float f0 = fmaf(dx, dx, d.z);
      dx = d.w - px1; const float f1 = fmaf(dx, dx, d.z);
      dx = d.w - px2; const float f2 = fmaf(dx, dx, d.z);
      dx = d.w - px3; const float f3 = fmaf(dx, dx, d.z);
      m0 = fminf(fminf(m0, e0), f0);               // -> v_min3_f32
      m1 = fminf(fminf(m1, e1), f1);
      m2 = fminf(fminf(m2, e2), f2);
      m3 = fminf(fminf(m3, e3), f3);
    }
  }

  float* o = out + (((v * 2 + h) * WIMG) + row) * WIMG + lane;
  o[0]   = 2.0f * exp2f(-CLOG2 * m0) - 1.0f;
  o[64]  = 2.0f * exp2f(-CLOG2 * m1) - 1.0f;
  o[128] = 2.0f * exp2f(-CLOG2 * m2) - 1.0f;
  o[192] = 2.0f * exp2f(-CLOG2 * m3) - 1.0f;
}

extern "C" void kernel_launch(void* const* d_in, const int* in_sizes, int n_in,
                              void* d_out, int out_size, void* d_ws, size_t ws_size,
                              hipStream_t stream) {
  const float* src = (const float*)d_in[0];   // (4096,3) f32
  const float* tgt = (const float*)d_in[1];   // (4096,3) f32
  float4* pts = (float4*)d_ws;                // 6*8192 float4 = 768 KiB
  float* out = (float*)d_out;                 // (6,2,256,256) f32

  prep_kernel<<<6, 256, 0, stream>>>(src, tgt, pts);
  render_kernel<<<768, 256, 0, stream>>>(pts, out);
}

// Round 2
// 108.996 us; speedup vs baseline: 2.0731x; 2.0731x over previous
//
#include <hip/hip_runtime.h>
#include <math.h>

// RegistrationRender: 6 views x (src,tgt) x 256x256 max-of-gaussians render.
//
// Math: v = pv_k * exp(-5000*d2)  ->  log2 v = log2(pv_k) - C*d2, C = 5000*log2(e)
//  max_k v = exp2(-C * min_k (dx^2 + dy^2 - log2(pv_k)/C))
// Culling: points farther than RCUT=0.084 from every pixel of a tile contribute
// < exp(-5000*0.084^2) = e^-35 ~ 5e-16 -> exactly-to-tolerance droppable.
// Grid bin (36x36, cell 0.06, span [-1.08,1.08]) per (view,half); per-tile
// candidate gather into LDS, then brute-force min over ~100-300 candidates.

#define NPTS 8192
#define HALF 4096
#define WIMG 256
#define CLOG2 7213.475204444817f          // 5000 * log2(e)
#define INV_CLOG2 1.3862943611198906e-4f  // ln(2)/5000

#define NC 36
#define NCELLS (NC * NC)                  // 1296 per (view,half); 12 grids
#define CAP 48
#define CELLW 0.06f
#define INV_CELL 16.666666666f
#define GMIN -1.08f
#define KEEP 1.076f
#define RCUT 0.084f
#define MAXCAND 2048
#define MAXCELLS 128

#define CNT_OFF 786432                    // after pts: 6*8192*16 B
#define LIST_OFF 851968
#define LIST_BYTES ((size_t)12 * NCELLS * CAP * 4)
#define WS_NEED (LIST_OFF + LIST_BYTES)   // ~3.84 MB

// Rotation matrices: exact f32 casts of numpy float64 cos/sin values.
static __device__ __constant__ float RMAT[6][9] = {
  { 1.f, 0.f, 0.f,   0.f, 1.f, 0.f,   0.f, 0.f, 1.f },
  { 6.123233995736766e-17f, 0.f, 1.f,  0.f, 1.f, 0.f,  -1.f, 0.f, 6.123233995736766e-17f },
  { -1.f, 0.f, 1.2246467991473532e-16f, 0.f, 1.f, 0.f, -1.2246467991473532e-16f, 0.f, -1.f },
  { -1.8369701987210297e-16f, 0.f, -1.f, 0.f, 1.f, 0.f,  1.f, 0.f, -1.8369701987210297e-16f },
  { 1.f, 0.f, 0.f,  0.f, 6.123233995736766e-17f, -1.f,  0.f, 1.f, 6.123233995736766e-17f },
  { 1.f, 0.f, 0.f,  0.f, -1.8369701987210297e-16f, 1.f, 0.f, -1.f, -1.8369701987210297e-16f },
};

// ---------------- kernel 1: rotate, depth min/max, {x,y,pen}; optional binning
__global__ __launch_bounds__(256) void prep_kernel(const float* __restrict__ src,
                                                   const float* __restrict__ tgt,
                                                   float4* __restrict__ pts,
                                                   int* __restrict__ cnt,
                                                   int* __restrict__ lists,
                                                   int use_grid) {
  const int v = blockIdx.x;
  const int tid = threadIdx.x;
  const float* R = RMAT[v];
  const float r20 = R[6], r21 = R[7], r22 = R[8];

  float zmin = 3.0e38f, zmax = -3.0e38f;
  for (int i = tid; i < NPTS; i += 256) {
    const float* p = (i < HALF) ? (src + 3 * i) : (tgt + 3 * (i - HALF));
    const float a = p[0], b = p[1], c = p[2];
    const float z = r20 * a + r21 * b + r22 * c;
    zmin = fminf(zmin, z);
    zmax = fmaxf(zmax, z);
  }
  for (int off = 32; off > 0; off >>= 1) {
    zmin = fminf(zmin, __shfl_down(zmin, off));
    zmax = fmaxf(zmax, __shfl_down(zmax, off));
  }
  __shared__ float smin[4], smax[4];
  const int lane = tid & 63, w = tid >> 6;
  if (lane == 0) { smin[w] = zmin; smax[w] = zmax; }
  __syncthreads();
  const float dmin = fminf(fminf(smin[0], smin[1]), fminf(smin[2], smin[3]));
  const float dmax = fmaxf(fmaxf(smax[0], smax[1]), fmaxf(smax[2], smax[3]));
  const float range = dmax - dmin;

  const float r00 = R[0], r01 = R[1], r02 = R[2];
  const float r10 = R[3], r11 = R[4], r12 = R[5];
  for (int i = tid; i < NPTS; i += 256) {
    const float* p = (i < HALF) ? (src + 3 * i) : (tgt + 3 * (i - HALF));
    const float a = p[0], b = p[1], c = p[2];
    const float x = r00 * a + r01 * b + r02 * c;
    const float y = r10 * a + r11 * b + r12 * c;
    const float z = r20 * a + r21 * b + r22 * c;
    const float pv = 1.0f - (z - dmin) / range;
    const float pen = (pv > 0.f) ? (-log2f(pv) * INV_CLOG2) : 1.0e26f;
    pts[v * NPTS + i] = make_float4(x, y, pen, 0.f);
    if (use_grid && fabsf(x) <= KEEP && fabsf(y) <= KEEP) {
      const int cx = (int)((x - GMIN) * INV_CELL);
      const int cy = (int)((y - GMIN) * INV_CELL);
      const int h = i >> 12;
      const int cell = (v * 2 + h) * NCELLS + cy * NC + cx;
      const int idx = atomicAdd(&cnt[cell], 1);
      if (idx < CAP) lists[(size_t)cell * CAP + idx] = i & (HALF - 1);
    }
  }
}

// ---------------- kernel 2a: grid-culled render. Block = (view,half,64x16 tile)
__global__ __launch_bounds__(256) void render_grid(const float4* __restrict__ pts,
                                                   const int* __restrict__ cnt,
                                                   const int* __restrict__ lists,
                                                   float* __restrict__ out) {
  __shared__ float4 sc[MAXCAND];
  __shared__ int s_cn[MAXCELLS];
  __shared__ int s_off[MAXCELLS];
  __shared__ int s_total;

  const int b = blockIdx.x;               // 768 = 12 images * 64 tiles
  const int tile = b & 63, vh = b >> 6;
  const int tx = tile & 3, ty = tile >> 2; // 4x16 tiles of 64x16 px
  const int col0 = tx << 6, row0 = ty << 4;
  const int tid = threadIdx.x;

  const float pxmin = (col0 - 127.5f) * 0.0078125f;
  const float pxmax = pxmin + 63.0f * 0.0078125f;
  const float pymin = (row0 - 127.5f) * 0.0078125f;
  const float pymax = pymin + 15.0f * 0.0078125f;
  const int cx0 = max(0, (int)floorf((pxmin - RCUT - GMIN) * INV_CELL));
  const int cx1 = min(NC - 1, (int)floorf((pxmax + RCUT - GMIN) * INV_CELL));
  const int cy0 = max(0, (int)floorf((pymin - RCUT - GMIN) * INV_CELL));
  const int cy1 = min(NC - 1, (int)floorf((pymax + RCUT - GMIN) * INV_CELL));
  const int nx = cx1 - cx0 + 1;
  const int ncl = nx * (cy1 - cy0 + 1);   // <= 13*6 = 78

  const int gbase = vh * NCELLS;
  for (int c = tid; c < MAXCELLS; c += 256) {
    int n = 0;
    if (c < ncl) {
      const int cell = gbase + (cy0 + c / nx) * NC + cx0 + c % nx;
      n = min(cnt[cell], CAP);
    }
    s_cn[c] = n;
  }
  __syncthreads();
  // exclusive scan over 128 cell counts, wave 0
  if (tid < 64) {
    const int a = s_cn[tid];
    const int b2 = s_cn[tid + 64];
    int sa = a;
#pragma unroll
    for (int o = 1; o < 64; o <<= 1) { int t = __shfl_up(sa, o); if (tid >= o) sa += t; }
    const int tot0 = __shfl(sa, 63);
    int sb = b2;
#pragma unroll
    for (int o = 1; o < 64; o <<= 1) { int t = __shfl_up(sb, o); if (tid >= o) sb += t; }
    s_off[tid] = sa - a;
    s_off[tid + 64] = tot0 + sb - b2;
    if (tid == 63) s_total = tot0 + sb;
  }
  __syncthreads();
  const int total = min(s_total, MAXCAND);
  const float4* pbase = pts + (vh >> 1) * NPTS + (vh & 1) * HALF;
  // dense parallel copy: all loads independent -> latency pipelined
  const int slots = ncl * CAP;
  for (int e = tid; e < slots; e += 256) {
    const int c = e / CAP, k = e - c * CAP;
    if (k < s_cn[c]) {
      const int cell = gbase + (cy0 + c / nx) * NC + cx0 + c % nx;
      const int gi = lists[(size_t)cell * CAP + k];
      const int ci = s_off[c] + k;
      if (ci < MAXCAND) sc[ci] = pbase[gi];
    }
  }
  __syncthreads();

  const int col = col0 + (tid & 63);
  const int r0 = row0 + (tid >> 6);       // rows r0, r0+4, r0+8, r0+12
  const float px = (col - 127.5f) * 0.0078125f;
  const float py0 = (r0 - 127.5f) * 0.0078125f;
  float m0 = 3.0e38f, m1 = 3.0e38f, m2 = 3.0e38f, m3 = 3.0e38f;
  for (int k = 0; k < total; ++k) {
    const float4 p = sc[k];               // broadcast read
    const float dx = p.x - px;
    const float c0 = fmaf(dx, dx, p.z);
    float dy;
    dy = p.y - py0;             m0 = fminf(m0, fmaf(dy, dy, c0));
    dy = p.y - py0 - 0.03125f;  m1 = fminf(m1, fmaf(dy, dy, c0));
    dy = p.y - py0 - 0.0625f;   m2 = fminf(m2, fmaf(dy, dy, c0));
    dy = p.y - py0 - 0.09375f;  m3 = fminf(m3, fmaf(dy, dy, c0));
  }
  float* o = out + (vh * 256 + r0) * 256 + col;
  o[0]    = 2.0f * exp2f(-CLOG2 * m0) - 1.0f;
  o[1024] = 2.0f * exp2f(-CLOG2 * m1) - 1.0f;
  o[2048] = 2.0f * exp2f(-CLOG2 * m2) - 1.0f;
  o[3072] = 2.0f * exp2f(-CLOG2 * m3) - 1.0f;
}

// ---------------- kernel 2b: fallback brute-force render (ws too small)
__device__ __forceinline__ void stage_chunk(const float4* __restrict__ base, int c,
                                            float4* __restrict__ dst, int lane, float py) {
  const int p0 = c * 256 + 2 * lane;
  const float4 a0 = base[p0];
  const float4 a1 = base[p0 + 1];
  const float4 b0 = base[p0 + 128];
  const float4 b1 = base[p0 + 129];
  float dy;
  dy = a0.y - py; const float E0 = fmaf(dy, dy, a0.z);
  dy = a1.y - py; const float E1 = fmaf(dy, dy, a1.z);
  dy = b0.y - py; const float E2 = fmaf(dy, dy, b0.z);
  dy = b1.y - py; const float E3 = fmaf(dy, dy, b1.z);
  dst[lane]      = make_float4(E0, a0.x, E1, a1.x);
  dst[64 + lane] = make_float4(E2, b0.x, E3, b1.x);
}

__global__ __launch_bounds__(256) void render_kernel(const float4* __restrict__ pts,
                                                     float* __restrict__ out) {
  __shared__ float4 sbuf[4][2][128];
  const int b = blockIdx.x;
  const int v = b >> 7, rp = b & 127;
  const int tid = threadIdx.x;
  const int w = tid >> 6, lane = tid & 63;
  const int row = 2 * rp + (w & 1);
  const int h = w >> 1;
  const float py  = (row - 127.5f) * 0.0078125f;
  const float px0 = (lane - 127.5f) * 0.0078125f;
  const float px1 = px0 + 0.5f;
  const float px2 = px0 + 1.0f;
  const float px3 = px0 + 1.5f;
  const float4* base = pts + v * NPTS + h * HALF;

  float m0 = 3.0e38f, m1 = 3.0e38f, m2 = 3.0e38f, m3 = 3.0e38f;
  stage_chunk(base, 0, sbuf[w][0], lane, py);
  for (int c = 0; c < 16; ++c) {
    __syncthreads();
    if (c < 15) stage_chunk(base, c + 1, sbuf[w][(c + 1) & 1], lane, py);
    const float4* q = sbuf[w][c & 1];
#pragma unroll 4
    for (int p = 0; p < 128; ++p) {
      const float4 d = q[p];
      float dx;
      dx = d.y - px0; const float e0 = fmaf(dx, dx, d.x);
      dx = d.y - px1; const float e1 = fmaf(dx, dx, d.x);
      dx = d.y - px2; const float e2 = fmaf(dx, dx, d.x);
      dx = d.y - px3; const float e3 = fmaf(dx, dx, d.x);
      dx = d.w - px0; const float f0 = fmaf(dx, dx, d.z);
      dx = d.w - px1; const float f1 = fmaf(dx, dx, d.z);
      dx = d.w - px2; const float f2 = fmaf(dx, dx, d.z);
      dx = d.w - px3; const float f3 = fmaf(dx, dx, d.z);
      m0 = fminf(fminf(m0, e0), f0);
      m1 = fminf(fminf(m1, e1), f1);
      m2 = fminf(fminf(m2, e2), f2);
      m3 = fminf(fminf(m3, e3), f3);
    }
  }
  float* o = out + (((v * 2 + h) * WIMG) + row) * WIMG + lane;
  o[0]   = 2.0f * exp2f(-CLOG2 * m0) - 1.0f;
  o[64]  = 2.0f * exp2f(-CLOG2 * m1) - 1.0f;
  o[128] = 2.0f * exp2f(-CLOG2 * m2) - 1.0f;
  o[192] = 2.0f * exp2f(-CLOG2 * m3) - 1.0f;
}

extern "C" void kernel_launch(void* const* d_in, const int* in_sizes, int n_in,
                              void* d_out, int out_size, void* d_ws, size_t ws_size,
                              hipStream_t stream) {
  const float* src = (const float*)d_in[0];   // (4096,3) f32
  const float* tgt = (const float*)d_in[1];   // (4096,3) f32
  float* out = (float*)d_out;                 // (6,2,256,256) f32
  float4* pts = (float4*)d_ws;
  int* cnt   = (int*)((char*)d_ws + CNT_OFF);
  int* lists = (int*)((char*)d_ws + LIST_OFF);

  if (ws_size >= WS_NEED) {
    hipMemsetAsync(cnt, 0, 12 * NCELLS * sizeof(int), stream);
    prep_kernel<<<6, 256, 0, stream>>>(src, tgt, pts, cnt, lists, 1);
    render_grid<<<768, 256, 0, stream>>>(pts, cnt, lists, out);
  } else {
    prep_kernel<<<6, 256, 0, stream>>>(src, tgt, pts, cnt, lists, 0);
    render_kernel<<<768, 256, 0, stream>>>(pts, out);
  }
}

// Round 3
// 69.730 us; speedup vs baseline: 3.2405x; 1.5631x over previous
//
#include <hip/hip_runtime.h>
#include <math.h>

// RegistrationRender: 6 views x (src,tgt) x 256x256 max-of-gaussians render.
// SINGLE fused kernel: block = (view, half, 64x16 pixel tile).
//
// Math: v = pv_k * exp(-5000*d2)  ->  max_k v = exp2(-C * min_k (dx^2+dy^2+pen_k)),
//   C = 5000*log2(e), pen_k = -log2(pv_k)/C  (pv=0 -> +1e26 -> contributes 0).
// Culling: points farther than RCUT=0.084 from every pixel of the tile give
//   wgt < e^-35 ~ 5e-16 -> droppable far below tolerance. Each block scans its
//   half's 4096 points (L2-resident), bbox-filters into LDS (~130 survive at the
//   densest tile), then brute-forces the min. Depth min/max recomputed per block
//   (fp min/max is exactly order-independent -> bitwise-identical dmin/dmax).
// Block->tile swizzle: blocks b, b+256, b+512 share a CU; stride 21 decorrelates
//   tile geometry (ty jumps ~5) so one CU never owns 3 center tiles.

#define WIMG 256
#define HALF 4096
#define CLOG2 7213.475204444817f          // 5000 * log2(e)
#define INV_CLOG2 1.3862943611198906e-4f  // ln(2)/5000
#define RCUT 0.084f
#define SCAP 2048

// Rotation matrices: exact f32 casts of numpy float64 cos/sin values.
static __device__ __constant__ float RMAT[6][9] = {
  { 1.f, 0.f, 0.f,   0.f, 1.f, 0.f,   0.f, 0.f, 1.f },
  { 6.123233995736766e-17f, 0.f, 1.f,  0.f, 1.f, 0.f,  -1.f, 0.f, 6.123233995736766e-17f },
  { -1.f, 0.f, 1.2246467991473532e-16f, 0.f, 1.f, 0.f, -1.2246467991473532e-16f, 0.f, -1.f },
  { -1.8369701987210297e-16f, 0.f, -1.f, 0.f, 1.f, 0.f,  1.f, 0.f, -1.8369701987210297e-16f },
  { 1.f, 0.f, 0.f,  0.f, 6.123233995736766e-17f, -1.f,  0.f, 1.f, 6.123233995736766e-17f },
  { 1.f, 0.f, 0.f,  0.f, -1.8369701987210297e-16f, 1.f, 0.f, -1.f, -1.8369701987210297e-16f },
};

__global__ __launch_bounds__(256) void fused_render(const float* __restrict__ src,
                                                    const float* __restrict__ tgt,
                                                    float* __restrict__ out) {
  __shared__ float4 sc[SCAP];            // {x, y, pen, 0} per surviving point
  __shared__ float smin[4], smax[4];
  __shared__ int s_n;

  const int b = blockIdx.x;              // 768 = 12 (view,half) * 64 tiles
  const int vh = b >> 6;
  const int tile = (b + 21 * vh) & 63;   // load-balance swizzle
  const int v = vh >> 1, h = vh & 1;
  const int tx = tile & 3, ty = tile >> 2;   // 4x16 tiles of 64x16 px
  const int col0 = tx << 6, row0 = ty << 4;
  const int tid = threadIdx.x;
  const int lane = tid & 63, w = tid >> 6;

  const float* R = RMAT[v];
  const float r00 = R[0], r01 = R[1], r02 = R[2];
  const float r10 = R[3], r11 = R[4], r12 = R[5];
  const float r20 = R[6], r21 = R[7], r22 = R[8];

  // ---- phase A: rotate all 8192 points, block-reduce depth min/max;
  //      keep own half's x,y,z in registers.
  const float* own = h ? tgt : src;
  const float* oth = h ? src : tgt;
  float zmin = 3.0e38f, zmax = -3.0e38f;
  float xs[16], ys[16], zs[16];
#pragma unroll
  for (int j = 0; j < 16; ++j) {
    const float* p = oth + 3 * (tid + 256 * j);
    const float a = p[0], bb = p[1], c = p[2];
    const float z = r20 * a + r21 * bb + r22 * c;
    zmin = fminf(zmin, z);
    zmax = fmaxf(zmax, z);
  }
#pragma unroll
  for (int j = 0; j < 16; ++j) {
    const float* p = own + 3 * (tid + 256 * j);
    const float a = p[0], bb = p[1], c = p[2];
    const float z = r20 * a + r21 * bb + r22 * c;
    zmin = fminf(zmin, z);
    zmax = fmaxf(zmax, z);
    xs[j] = r00 * a + r01 * bb + r02 * c;
    ys[j] = r10 * a + r11 * bb + r12 * c;
    zs[j] = z;
  }
#pragma unroll
  for (int off = 32; off > 0; off >>= 1) {
    zmin = fminf(zmin, __shfl_down(zmin, off));
    zmax = fmaxf(zmax, __shfl_down(zmax, off));
  }
  if (tid == 0) s_n = 0;
  if (lane == 0) { smin[w] = zmin; smax[w] = zmax; }
  __syncthreads();
  const float dmin = fminf(fminf(smin[0], smin[1]), fminf(smin[2], smin[3]));
  const float dmax = fmaxf(fmaxf(smax[0], smax[1]), fmaxf(smax[2], smax[3]));
  const float range = dmax - dmin;

  // ---- phase B: bbox filter own half into LDS (pen computed lazily)
  const float pxmin = (col0 - 127.5f) * 0.0078125f;
  const float pymin = (row0 - 127.5f) * 0.0078125f;
  const float bx0 = pxmin - RCUT, bx1 = pxmin + 63.0f * 0.0078125f + RCUT;
  const float by0 = pymin - RCUT, by1 = pymin + 15.0f * 0.0078125f + RCUT;
#pragma unroll
  for (int j = 0; j < 16; ++j) {
    const float x = xs[j], y = ys[j];
    if (x >= bx0 && x <= bx1 && y >= by0 && y <= by1) {
      const float pv = 1.0f - (zs[j] - dmin) / range;   // same op order as ref
      const float pen = (pv > 0.f) ? (-log2f(pv) * INV_CLOG2) : 1.0e26f;
      const int idx = atomicAdd(&s_n, 1);
      if (idx < SCAP) sc[idx] = make_float4(x, y, pen, 0.f);
    }
  }
  __syncthreads();
  const int total = min(s_n, SCAP);

  // ---- phase C: min over candidates, 4 pixels/thread (1 col x 4 rows)
  const float px  = (col0 + lane - 127.5f) * 0.0078125f;
  const float py0 = (row0 + w - 127.5f) * 0.0078125f;   // rows w, w+4, w+8, w+12
  const float py1 = py0 + 0.03125f;
  const float py2 = py0 + 0.0625f;
  const float py3 = py0 + 0.09375f;
  float m0 = 3.0e38f, m1 = 3.0e38f, m2 = 3.0e38f, m3 = 3.0e38f;
  int k = 0;
  for (; k + 1 < total; k += 2) {
    const float4 A = sc[k];              // broadcast reads
    const float4 B = sc[k + 1];
    const float dxa = A.x - px; const float ca = fmaf(dxa, dxa, A.z);
    const float dxb = B.x - px; const float cb = fmaf(dxb, dxb, B.z);
    float da, db;
    da = A.y - py0; db = B.y - py0;
    m0 = fminf(fminf(m0, fmaf(da, da, ca)), fmaf(db, db, cb));
    da = A.y - py1; db = B.y - py1;
    m1 = fminf(fminf(m1, fmaf(da, da, ca)), fmaf(db, db, cb));
    da = A.y - py2; db = B.y - py2;
    m2 = fminf(fminf(m2, fmaf(da, da, ca)), fmaf(db, db, cb));
    da = A.y - py3; db = B.y - py3;
    m3 = fminf(fminf(m3, fmaf(da, da, ca)), fmaf(db, db, cb));
  }
  if (k < total) {
    const float4 A = sc[k];
    const float dxa = A.x - px; const float ca = fmaf(dxa, dxa, A.z);
    float da;
    da = A.y - py0; m0 = fminf(m0, fmaf(da, da, ca));
    da = A.y - py1; m1 = fminf(m1, fmaf(da, da, ca));
    da = A.y - py2; m2 = fminf(m2, fmaf(da, da, ca));
    da = A.y - py3; m3 = fminf(m3, fmaf(da, da, ca));
  }

  float* o = out + (vh * WIMG + row0 + w) * WIMG + col0 + lane;
  o[0]    = 2.0f * exp2f(-CLOG2 * m0) - 1.0f;
  o[1024] = 2.0f * exp2f(-CLOG2 * m1) - 1.0f;
  o[2048] = 2.0f * exp2f(-CLOG2 * m2) - 1.0f;
  o[3072] = 2.0f * exp2f(-CLOG2 * m3) - 1.0f;
}

extern "C" void kernel_launch(void* const* d_in, const int* in_sizes, int n_in,
                              void* d_out, int out_size, void* d_ws, size_t ws_size,
                              hipStream_t stream) {
  const float* src = (const float*)d_in[0];   // (4096,3) f32
  const float* tgt = (const float*)d_in[1];   // (4096,3) f32
  float* out = (float*)d_out;                 // (6,2,256,256) f32
  (void)d_ws; (void)ws_size;
  fused_render<<<768, 256, 0, stream>>>(src, tgt, out);
}